// Round 4
// baseline (129.323 us; speedup 1.0000x reference)
//
#include <hip/hip_runtime.h>

// LengthRegulator fused: per-block redundant scan of durations + float4 gather.
// out[b,f,:] = x[b, searchsorted_right(cum[b], f), :] * (f < min(mel,max_len))
// mel_len[b] = sum(durations[b])  (written as f32 at the tail of d_out)

#define B_ 16
#define T_ 512
#define D_ 384
#define MAXLEN_ 4096
#define ROWV4_ (D_ / 4)                 // 96 float4 per row
#define OUT_ELEMS_ (B_ * MAXLEN_ * D_) // 25,165,824
#define BLK_ 1024
#define BLOCKS_PER_BATCH_ ((MAXLEN_ * ROWV4_) / BLK_) // 384
#define GRID_ (B_ * BLOCKS_PER_BATCH_)                // 6144

typedef float v4f __attribute__((ext_vector_type(4))); // native vec for nontemporal builtin

__global__ __launch_bounds__(BLK_) void lr_fused_kernel(const v4f* __restrict__ x,
                                                        const int* __restrict__ dur,
                                                        const int* __restrict__ max_len_p,
                                                        v4f* __restrict__ out,
                                                        float* __restrict__ mel_out) {
    __shared__ int s[T_];
    __shared__ int wsum[8];
    const int t = threadIdx.x;
    const int b = blockIdx.x / BLOCKS_PER_BATCH_;

    // --- redundant per-block inclusive scan of this batch's 512 durations ---
    int v = 0;
    const int lane = t & 63, w = t >> 6;
    if (t < T_) {
        v = dur[b * T_ + t];
        #pragma unroll
        for (int off = 1; off < 64; off <<= 1) {
            int n = __shfl_up(v, off);
            if (lane >= off) v += n;
        }
        if (lane == 63) wsum[w] = v;
    }
    __syncthreads();
    if (t < 8) { // scan the 8 wave totals (lanes 0..7 of wave 0)
        int u = wsum[t];
        #pragma unroll
        for (int off = 1; off < 8; off <<= 1) {
            int n = __shfl_up(u, off);
            if (t >= off) u += n;
        }
        wsum[t] = u;
    }
    __syncthreads();
    if (t < T_) s[t] = v + (w > 0 ? wsum[w - 1] : 0);
    __syncthreads();

    // --- gather: one float4 per thread, coalesced nontemporal write ---
    const int g = blockIdx.x * BLK_ + t;
    const int row = g / ROWV4_;           // b*MAXLEN + f
    const int col = g - row * ROWV4_;
    const int f = row & (MAXLEN_ - 1);
    const int mel = s[T_ - 1];
    const int max_len = max_len_p[0];

    v4f ov = (v4f){0.f, 0.f, 0.f, 0.f};
    if (f < mel && f < max_len) {
        // searchsorted(cum, f, 'right') = #{i : cum[i] <= f}; 9-step branchless
        int idx = 0;
        #pragma unroll
        for (int step = 256; step > 0; step >>= 1)
            if (s[idx + step - 1] <= f) idx += step;
        if (idx > T_ - 1) idx = T_ - 1; // safety clip (unreachable given f < mel)
        ov = x[(b * T_ + idx) * ROWV4_ + col];
    }
    __builtin_nontemporal_store(ov, &out[g]);

    if (t == 0 && (blockIdx.x % BLOCKS_PER_BATCH_) == 0)
        mel_out[b] = (float)mel;
}

extern "C" void kernel_launch(void* const* d_in, const int* in_sizes, int n_in,
                              void* d_out, int out_size, void* d_ws, size_t ws_size,
                              hipStream_t stream) {
    const float* x = (const float*)d_in[0];
    const int* dur = (const int*)d_in[1];
    const int* max_len_p = (const int*)d_in[2]; // device scalar — read in-kernel only

    float* out = (float*)d_out;
    float* mel_out = out + OUT_ELEMS_;
    (void)d_ws; (void)ws_size;

    lr_fused_kernel<<<GRID_, BLK_, 0, stream>>>(
        (const v4f*)x, dur, max_len_p, (v4f*)out, mel_out);
}

// Round 5
// 122.906 us; speedup vs baseline: 1.0522x; 1.0522x over previous
//
#include <hip/hip_runtime.h>

// LengthRegulator: B=16, T=512, D=384, MAX_LEN=4096
// out[b,f,:] = x[b, searchsorted_right(cum[b], f).clip(0,T-1), :] * (f < min(mel,max_len))
// mel_len[b] = sum(durations[b])  (written as f32 at the tail of d_out)
//
// R5 = exact revert to the R2 two-kernel structure (best measured: 121.7 µs).
// R4's fused+nontemporal variant regressed (129.3 µs, partly clock drift,
// partly NT-store/1024-block barrier cost). Controllable work here is
// ~100.7 MB coalesced write + ~20 MB fetch ≈ 20 µs — the write-BW floor.

#define B_ 16
#define T_ 512
#define D_ 384
#define MAXLEN_ 4096
#define ROWV4_ (D_ / 4)                 // 96 float4 per row
#define OUT_ELEMS_ (B_ * MAXLEN_ * D_) // 25,165,824
#define BLOCKS_PER_BATCH_ ((MAXLEN_ * ROWV4_) / 256) // 1536 — block never spans batches

// Kernel 1: per-batch inclusive cumsum -> ws (B*T ints); mel_len -> d_out tail.
__global__ __launch_bounds__(T_) void lr_scan_kernel(const int* __restrict__ dur,
                                                     int* __restrict__ cum_ws,
                                                     float* __restrict__ mel_out) {
    const int b = blockIdx.x, t = threadIdx.x;
    const int lane = t & 63, w = t >> 6;
    int v = dur[b * T_ + t];
    #pragma unroll
    for (int off = 1; off < 64; off <<= 1) {
        int n = __shfl_up(v, off);
        if (lane >= off) v += n;
    }
    __shared__ int wsum[8];
    if (lane == 63) wsum[w] = v;
    __syncthreads();
    if (t < 8) { // scan the 8 wave totals (lanes 0..7 of wave 0)
        int u = wsum[t];
        #pragma unroll
        for (int off = 1; off < 8; off <<= 1) {
            int n = __shfl_up(u, off);
            if (t >= off) u += n;
        }
        wsum[t] = u;
    }
    __syncthreads();
    const int cum = v + (w > 0 ? wsum[w - 1] : 0);
    cum_ws[b * T_ + t] = cum;
    if (t == T_ - 1) mel_out[b] = (float)cum;
}

// Kernel 2: per-block LDS copy of this batch's cum, branchless binary search
// per output row, float4 gather + coalesced write.
__global__ __launch_bounds__(256) void lr_gather_kernel(const float4* __restrict__ x,
                                                        const int* __restrict__ cum_ws,
                                                        const int* __restrict__ max_len_p,
                                                        float4* __restrict__ out) {
    __shared__ int s[T_];
    const int t = threadIdx.x;
    const int b = blockIdx.x / BLOCKS_PER_BATCH_;
    const int* cb = cum_ws + b * T_;
    s[t] = cb[t];
    s[t + 256] = cb[t + 256];
    __syncthreads();

    const int g = blockIdx.x * 256 + t;   // one float4 per thread
    const int row = g / ROWV4_;           // global row = b*MAXLEN + f
    const int col = g - row * ROWV4_;
    const int f = row & (MAXLEN_ - 1);
    const int mel = s[T_ - 1];
    const int max_len = max_len_p[0];

    float4 v = make_float4(0.f, 0.f, 0.f, 0.f);
    if (f < mel && f < max_len) {
        // searchsorted(cum, f, 'right') = #{i : cum[i] <= f}; 9-step branchless
        int idx = 0;
        #pragma unroll
        for (int step = 256; step > 0; step >>= 1)
            if (s[idx + step - 1] <= f) idx += step;
        if (idx > T_ - 1) idx = T_ - 1; // safety clip (unreachable given f < mel)
        v = x[(b * T_ + idx) * ROWV4_ + col];
    }
    out[g] = v;
}

extern "C" void kernel_launch(void* const* d_in, const int* in_sizes, int n_in,
                              void* d_out, int out_size, void* d_ws, size_t ws_size,
                              hipStream_t stream) {
    const float* x = (const float*)d_in[0];
    const int* dur = (const int*)d_in[1];
    const int* max_len_p = (const int*)d_in[2]; // device scalar — read in-kernel only

    float* out = (float*)d_out;
    float* mel_out = out + OUT_ELEMS_;
    int* cum_ws = (int*)d_ws; // B*T ints = 32 KB scratch

    lr_scan_kernel<<<B_, T_, 0, stream>>>(dur, cum_ws, mel_out);

    const int total_v4 = OUT_ELEMS_ / 4; // 6,291,456
    lr_gather_kernel<<<total_v4 / 256, 256, 0, stream>>>(
        (const float4*)x, cum_ws, max_len_p, (float4*)out);
}